// Round 1
// baseline (1818.055 us; speedup 1.0000x reference)
//
#include <hip/hip_runtime.h>
#include <math.h>

#define HDIM 128

// ---------------- degree / dinv ----------------
__global__ void deg_kernel(const int* __restrict__ dst, float* __restrict__ deg, int E) {
    int i = blockIdx.x * blockDim.x + threadIdx.x;
    int stride = gridDim.x * blockDim.x;
    for (; i < E; i += stride) atomicAdd(&deg[dst[i]], 1.0f);
}

__global__ void dinv_kernel(float* __restrict__ deg, int N) {
    int i = blockIdx.x * blockDim.x + threadIdx.x;
    if (i < N) deg[i] = rsqrtf(deg[i] + 1.0f);
}

// ---------------- GEMM: C[N x 128] = A[N x 128] @ B[128 x 128] (+bias) ----------------
// block 256 threads = 16(tx) x 16(ty); tile 64 rows x 128 cols; B staged in LDS (64KB)
__global__ __launch_bounds__(256) void gemm128(const float* __restrict__ A,
                                               const float* __restrict__ B,
                                               const float* __restrict__ bias,
                                               float* __restrict__ C, int N) {
    __shared__ float Bs[128 * 128];
    {
        const float4* B4 = (const float4*)B;
        float4* Bs4 = (float4*)Bs;
        #pragma unroll
        for (int i = 0; i < 16; i++) Bs4[threadIdx.x + i * 256] = B4[threadIdx.x + i * 256];
    }
    __syncthreads();

    int tx = threadIdx.x & 15;   // col group: cols tx*8 .. tx*8+7
    int ty = threadIdx.x >> 4;   // row group: rows ty*4 .. ty*4+3
    int row0 = blockIdx.x * 64 + ty * 4;
    int col0 = tx * 8;

    float4 acc[4][2];
    float4 bz0 = make_float4(0.f, 0.f, 0.f, 0.f), bz1 = bz0;
    if (bias) {
        bz0 = *(const float4*)(bias + col0);
        bz1 = *(const float4*)(bias + col0 + 4);
    }
    #pragma unroll
    for (int i = 0; i < 4; i++) { acc[i][0] = bz0; acc[i][1] = bz1; }

    // clamp rows for loads; stores guarded
    int r[4];
    #pragma unroll
    for (int i = 0; i < 4; i++) r[i] = min(row0 + i, N - 1);

    for (int k = 0; k < 128; k += 4) {
        float4 a[4];
        #pragma unroll
        for (int i = 0; i < 4; i++) a[i] = *(const float4*)(A + (size_t)r[i] * 128 + k);
        #pragma unroll
        for (int kk = 0; kk < 4; kk++) {
            float4 b0 = *(const float4*)(&Bs[(k + kk) * 128 + col0]);
            float4 b1 = *(const float4*)(&Bs[(k + kk) * 128 + col0 + 4]);
            #pragma unroll
            for (int i = 0; i < 4; i++) {
                float av = (kk == 0) ? a[i].x : (kk == 1) ? a[i].y : (kk == 2) ? a[i].z : a[i].w;
                acc[i][0].x += av * b0.x; acc[i][0].y += av * b0.y;
                acc[i][0].z += av * b0.z; acc[i][0].w += av * b0.w;
                acc[i][1].x += av * b1.x; acc[i][1].y += av * b1.y;
                acc[i][1].z += av * b1.z; acc[i][1].w += av * b1.w;
            }
        }
    }

    #pragma unroll
    for (int i = 0; i < 4; i++) {
        int rr = row0 + i;
        if (rr < N) {
            *(float4*)(C + (size_t)rr * 128 + col0) = acc[i][0];
            *(float4*)(C + (size_t)rr * 128 + col0 + 4) = acc[i][1];
        }
    }
}

// ---------------- edge scatter: agg[dst] += dinv[src]*dinv[dst] * hw[src] ----------------
// one wave per edge; lane covers feature f=lane and f=lane+64
__global__ __launch_bounds__(256) void scatter_kernel(const float* __restrict__ hw,
                                                      const int* __restrict__ src,
                                                      const int* __restrict__ dst,
                                                      const float* __restrict__ dinv,
                                                      float* __restrict__ agg, int E) {
    int lane = threadIdx.x & 63;
    int wid = (int)((blockIdx.x * blockDim.x + threadIdx.x) >> 6);
    int nw = (gridDim.x * blockDim.x) >> 6;
    for (int e = wid; e < E; e += nw) {
        int s = src[e], d = dst[e];
        float nrm = dinv[s] * dinv[d];
        const float* row = hw + (size_t)s * HDIM;
        float v0 = row[lane];
        float v1 = row[lane + 64];
        float* out = agg + (size_t)d * HDIM;
        atomicAdd(out + lane, nrm * v0);
        atomicAdd(out + lane + 64, nrm * v1);
    }
}

// ---------------- finalize: agg += dinv^2*hw + bias ; optional relu (in-place) ----------------
__global__ void finalize_kernel(float* __restrict__ agg, const float* __restrict__ hw,
                                const float* __restrict__ dinv, const float* __restrict__ bias,
                                int N, int relu) {
    size_t i = (size_t)blockIdx.x * blockDim.x + threadIdx.x;
    size_t total = (size_t)N * 32;
    if (i >= total) return;
    int n = (int)(i >> 5);
    int c4 = (int)(i & 31);
    float di = dinv[n];
    float sl = di * di;
    float4 v = ((const float4*)hw)[i];
    float4 a = ((float4*)agg)[i];
    float4 b = ((const float4*)bias)[c4];
    a.x += sl * v.x + b.x;
    a.y += sl * v.y + b.y;
    a.z += sl * v.z + b.z;
    a.w += sl * v.w + b.w;
    if (relu) {
        a.x = fmaxf(a.x, 0.f); a.y = fmaxf(a.y, 0.f);
        a.z = fmaxf(a.z, 0.f); a.w = fmaxf(a.w, 0.f);
    }
    ((float4*)agg)[i] = a;
}

// ---------------- batchnorm stats: per-feature sum & sumsq ----------------
__global__ __launch_bounds__(256) void bn_stats_kernel(const float* __restrict__ h,
                                                       float* __restrict__ stats, int N) {
    int f = threadIdx.x & 127;
    int half = threadIdx.x >> 7;  // 0..1
    float s = 0.f, s2 = 0.f;
    for (int n = blockIdx.x * 2 + half; n < N; n += gridDim.x * 2) {
        float v = h[(size_t)n * HDIM + f];
        s += v;
        s2 += v * v;
    }
    __shared__ float ls[256], ls2[256];
    ls[threadIdx.x] = s;
    ls2[threadIdx.x] = s2;
    __syncthreads();
    if (half == 0) {
        s = ls[f] + ls[f + 128];
        s2 = ls2[f] + ls2[f + 128];
        atomicAdd(&stats[f], s);
        atomicAdd(&stats[128 + f], s2);
    }
}

__global__ void bn_apply_kernel(float* __restrict__ hbuf, const float* __restrict__ stats,
                                const float* __restrict__ gamma, const float* __restrict__ beta,
                                int N) {
    size_t i = (size_t)blockIdx.x * blockDim.x + threadIdx.x;
    size_t total = (size_t)N * 32;
    if (i >= total) return;
    int c4 = (int)(i & 31);
    float4 s = ((const float4*)stats)[c4];
    float4 q = ((const float4*)(stats + 128))[c4];
    float4 gm = ((const float4*)gamma)[c4];
    float4 bt = ((const float4*)beta)[c4];
    float inv = 1.0f / (float)N;
    float4 v = ((float4*)hbuf)[i];
    float m, var, sc;
    m = s.x * inv; var = q.x * inv - m * m; sc = gm.x * rsqrtf(var + 1e-5f); v.x = (v.x - m) * sc + bt.x;
    m = s.y * inv; var = q.y * inv - m * m; sc = gm.y * rsqrtf(var + 1e-5f); v.y = (v.y - m) * sc + bt.y;
    m = s.z * inv; var = q.z * inv - m * m; sc = gm.z * rsqrtf(var + 1e-5f); v.z = (v.z - m) * sc + bt.z;
    m = s.w * inv; var = q.w * inv - m * m; sc = gm.w * rsqrtf(var + 1e-5f); v.w = (v.w - m) * sc + bt.w;
    ((float4*)hbuf)[i] = v;
}

// ---------------- pool: batch is sorted -> per-graph contiguous range ----------------
__device__ __forceinline__ int lower_bound_i(const int* __restrict__ arr, int n, int val) {
    int lo = 0, hi = n;
    while (lo < hi) {
        int mid = (lo + hi) >> 1;
        if (arr[mid] < val) lo = mid + 1; else hi = mid;
    }
    return lo;
}

__global__ void pool_kernel(const float* __restrict__ h, const int* __restrict__ batch,
                            float* __restrict__ out, int N, int G) {
    int g = blockIdx.x;
    int lo = lower_bound_i(batch, N, g);
    int hi = lower_bound_i(batch, N, g + 1);
    int f = threadIdx.x;  // 128 threads
    float s = 0.f;
    for (int n = lo; n < hi; n++) s += h[(size_t)n * HDIM + f];
    float cnt = (float)(hi - lo);
    out[(size_t)g * HDIM + f] = s / fmaxf(cnt, 1.0f);
}

// ---------------- launch ----------------
extern "C" void kernel_launch(void* const* d_in, const int* in_sizes, int n_in,
                              void* d_out, int out_size, void* d_ws, size_t ws_size,
                              hipStream_t stream) {
    const float* x      = (const float*)d_in[0];
    const int*   ei     = (const int*)d_in[1];
    const int*   batch  = (const int*)d_in[2];
    const float* W_emb  = (const float*)d_in[3];
    const float* b_emb  = (const float*)d_in[4];
    const float* W_conv = (const float*)d_in[5];
    const float* b_conv = (const float*)d_in[6];
    const float* gamma  = (const float*)d_in[7];
    const float* beta   = (const float*)d_in[8];

    const int E = in_sizes[1] / 2;
    const int N = in_sizes[2];
    const int G = out_size / HDIM;
    const int DEPTH = 4;

    const int* srcp = ei;
    const int* dstp = ei + E;
    float* out = (float*)d_out;

    float* ws = (float*)d_ws;
    size_t NH = (size_t)N * HDIM;
    size_t npad = ((size_t)N + 63) & ~(size_t)63;
    float* dinv  = ws;
    float* hbuf  = ws + npad;
    float* hwbuf = hbuf + NH;
    float* aggbuf = hwbuf + NH;
    float* stats = aggbuf + NH;

    // degrees
    hipMemsetAsync(dinv, 0, (size_t)N * sizeof(float), stream);
    deg_kernel<<<1024, 256, 0, stream>>>(dstp, dinv, E);
    dinv_kernel<<<(N + 255) / 256, 256, 0, stream>>>(dinv, N);

    // embedding
    gemm128<<<(N + 63) / 64, 256, 0, stream>>>(x, W_emb, b_emb, hbuf, N);

    float* h = hbuf;
    float* hw = hwbuf;
    float* agg = aggbuf;
    int ew_blocks = (int)((NH / 4 + 255) / 256);

    for (int l = 0; l < DEPTH; l++) {
        gemm128<<<(N + 63) / 64, 256, 0, stream>>>(h, W_conv + (size_t)l * HDIM * HDIM, nullptr, hw, N);
        hipMemsetAsync(agg, 0, NH * sizeof(float), stream);
        scatter_kernel<<<2048, 256, 0, stream>>>(hw, srcp, dstp, dinv, agg, E);
        finalize_kernel<<<ew_blocks, 256, 0, stream>>>(agg, hw, dinv, b_conv + (size_t)l * HDIM, N, (l < DEPTH - 1) ? 1 : 0);
        if (l < DEPTH - 1) {
            hipMemsetAsync(stats, 0, 256 * sizeof(float), stream);
            bn_stats_kernel<<<512, 256, 0, stream>>>(agg, stats, N);
            bn_apply_kernel<<<ew_blocks, 256, 0, stream>>>(agg, stats, gamma + (size_t)l * HDIM, beta + (size_t)l * HDIM, N);
        }
        float* t = h; h = agg; agg = t;
    }

    pool_kernel<<<G, HDIM, 0, stream>>>(h, batch, out, N, G);
}

// Round 3
// 735.645 us; speedup vs baseline: 2.4714x; 2.4714x over previous
//
#include <hip/hip_runtime.h>
#include <math.h>

#define HDIM 128

// ---------------- degree (int) ----------------
__global__ void deg_kernel(const int* __restrict__ dst, int* __restrict__ deg, int E) {
    int i = blockIdx.x * blockDim.x + threadIdx.x;
    int stride = gridDim.x * blockDim.x;
    for (; i < E; i += stride) atomicAdd(&deg[dst[i]], 1);
}

__global__ void dinv_kernel(const int* __restrict__ deg, float* __restrict__ dinv, int N) {
    int i = blockIdx.x * blockDim.x + threadIdx.x;
    if (i < N) dinv[i] = rsqrtf((float)deg[i] + 1.0f);
}

// ---------------- exclusive scan over deg -> offs[0..N] (single block) ----------------
__global__ __launch_bounds__(256) void scan_kernel(const int* __restrict__ deg,
                                                   int* __restrict__ offs, int N) {
    __shared__ int part[256];
    int chunk = (N + 255) / 256;
    int lo = threadIdx.x * chunk;
    int hi = min(lo + chunk, N);
    int s = 0;
    for (int i = lo; i < hi; i++) s += deg[i];
    part[threadIdx.x] = s;
    __syncthreads();
    // inclusive Hillis-Steele scan of 256 partials
    for (int off = 1; off < 256; off <<= 1) {
        int t = (threadIdx.x >= off) ? part[threadIdx.x - off] : 0;
        __syncthreads();
        part[threadIdx.x] += t;
        __syncthreads();
    }
    int run = part[threadIdx.x] - s;  // exclusive prefix for this chunk
    for (int i = lo; i < hi; i++) {
        offs[i] = run;
        run += deg[i];
    }
    if (threadIdx.x == 255) offs[N] = part[255];
}

// ---------------- CSR fill: csr_src[offs[d] + rank] = src ----------------
__global__ void fill_kernel(const int* __restrict__ src, const int* __restrict__ dst,
                            const int* __restrict__ offs, int* __restrict__ cursor,
                            int* __restrict__ csr_src, int E) {
    int i = blockIdx.x * blockDim.x + threadIdx.x;
    int stride = gridDim.x * blockDim.x;
    for (; i < E; i += stride) {
        int d = dst[i];
        int pos = atomicAdd(&cursor[d], 1);
        csr_src[offs[d] + pos] = src[i];
    }
}

// ---------------- GEMM: C[N x 128] = A[N x 128] @ B[128 x 128] (+bias) (*rowscale) ----------------
__global__ __launch_bounds__(256) void gemm128(const float* __restrict__ A,
                                               const float* __restrict__ B,
                                               const float* __restrict__ bias,
                                               const float* __restrict__ rowscale,
                                               float* __restrict__ C, int N) {
    __shared__ float Bs[128 * 128];
    {
        const float4* B4 = (const float4*)B;
        float4* Bs4 = (float4*)Bs;
        #pragma unroll
        for (int i = 0; i < 16; i++) Bs4[threadIdx.x + i * 256] = B4[threadIdx.x + i * 256];
    }
    __syncthreads();

    int tx = threadIdx.x & 15;   // col group: cols tx*8 .. tx*8+7
    int ty = threadIdx.x >> 4;   // row group: rows ty*4 .. ty*4+3
    int row0 = blockIdx.x * 64 + ty * 4;
    int col0 = tx * 8;

    float4 acc[4][2];
    float4 bz0 = make_float4(0.f, 0.f, 0.f, 0.f), bz1 = bz0;
    if (bias) {
        bz0 = *(const float4*)(bias + col0);
        bz1 = *(const float4*)(bias + col0 + 4);
    }
    #pragma unroll
    for (int i = 0; i < 4; i++) { acc[i][0] = bz0; acc[i][1] = bz1; }

    int r[4];
    #pragma unroll
    for (int i = 0; i < 4; i++) r[i] = min(row0 + i, N - 1);

    for (int k = 0; k < 128; k += 4) {
        float4 a[4];
        #pragma unroll
        for (int i = 0; i < 4; i++) a[i] = *(const float4*)(A + (size_t)r[i] * 128 + k);
        #pragma unroll
        for (int kk = 0; kk < 4; kk++) {
            float4 b0 = *(const float4*)(&Bs[(k + kk) * 128 + col0]);
            float4 b1 = *(const float4*)(&Bs[(k + kk) * 128 + col0 + 4]);
            #pragma unroll
            for (int i = 0; i < 4; i++) {
                float av = (kk == 0) ? a[i].x : (kk == 1) ? a[i].y : (kk == 2) ? a[i].z : a[i].w;
                acc[i][0].x += av * b0.x; acc[i][0].y += av * b0.y;
                acc[i][0].z += av * b0.z; acc[i][0].w += av * b0.w;
                acc[i][1].x += av * b1.x; acc[i][1].y += av * b1.y;
                acc[i][1].z += av * b1.z; acc[i][1].w += av * b1.w;
            }
        }
    }

    #pragma unroll
    for (int i = 0; i < 4; i++) {
        int rr = row0 + i;
        if (rr < N) {
            float sc = rowscale ? rowscale[rr] : 1.0f;
            float4 o0 = acc[i][0], o1 = acc[i][1];
            o0.x *= sc; o0.y *= sc; o0.z *= sc; o0.w *= sc;
            o1.x *= sc; o1.y *= sc; o1.z *= sc; o1.w *= sc;
            *(float4*)(C + (size_t)rr * 128 + col0) = o0;
            *(float4*)(C + (size_t)rr * 128 + col0 + 4) = o1;
        }
    }
}

// ---------------- gather: out[d] = dinv[d]*(sum_{s in in(d)} hws[s] + hws[d]) + bias ----------------
// one wave per node; lane covers features 2*lane, 2*lane+1 (float2)
__global__ __launch_bounds__(256) void gather_kernel(const float* __restrict__ hws,
                                                     const int* __restrict__ csr_src,
                                                     const int* __restrict__ offs,
                                                     const float* __restrict__ dinv,
                                                     const float* __restrict__ bias,
                                                     float* __restrict__ out,
                                                     int N, int relu) {
    int lane = threadIdx.x & 63;
    int node = blockIdx.x * 4 + (threadIdx.x >> 6);
    if (node >= N) return;
    int lo = offs[node], hi = offs[node + 1];

    float2 acc = make_float2(0.f, 0.f);
    int j = lo;
    for (; j + 3 < hi; j += 4) {
        int s0 = csr_src[j], s1 = csr_src[j + 1], s2 = csr_src[j + 2], s3 = csr_src[j + 3];
        float2 v0 = ((const float2*)(hws + (size_t)s0 * HDIM))[lane];
        float2 v1 = ((const float2*)(hws + (size_t)s1 * HDIM))[lane];
        float2 v2 = ((const float2*)(hws + (size_t)s2 * HDIM))[lane];
        float2 v3 = ((const float2*)(hws + (size_t)s3 * HDIM))[lane];
        acc.x += v0.x + v1.x + v2.x + v3.x;
        acc.y += v0.y + v1.y + v2.y + v3.y;
    }
    for (; j < hi; j++) {
        int s = csr_src[j];
        float2 v = ((const float2*)(hws + (size_t)s * HDIM))[lane];
        acc.x += v.x; acc.y += v.y;
    }
    // self-loop
    float2 vs = ((const float2*)(hws + (size_t)node * HDIM))[lane];
    float di = dinv[node];
    float2 b = ((const float2*)bias)[lane];
    float ox = di * (acc.x + vs.x) + b.x;
    float oy = di * (acc.y + vs.y) + b.y;
    if (relu) { ox = fmaxf(ox, 0.f); oy = fmaxf(oy, 0.f); }
    ((float2*)(out + (size_t)node * HDIM))[lane] = make_float2(ox, oy);
}

// ---------------- batchnorm stats: per-feature sum & sumsq ----------------
__global__ __launch_bounds__(256) void bn_stats_kernel(const float* __restrict__ h,
                                                       float* __restrict__ stats, int N) {
    int f = threadIdx.x & 127;
    int half = threadIdx.x >> 7;  // 0..1
    float s = 0.f, s2 = 0.f;
    for (int n = blockIdx.x * 2 + half; n < N; n += gridDim.x * 2) {
        float v = h[(size_t)n * HDIM + f];
        s += v;
        s2 += v * v;
    }
    __shared__ float ls[256], ls2[256];
    ls[threadIdx.x] = s;
    ls2[threadIdx.x] = s2;
    __syncthreads();
    if (half == 0) {
        s = ls[f] + ls[f + 128];
        s2 = ls2[f] + ls2[f + 128];
        atomicAdd(&stats[f], s);
        atomicAdd(&stats[128 + f], s2);
    }
}

__global__ void bn_apply_kernel(float* __restrict__ hbuf, const float* __restrict__ stats,
                                const float* __restrict__ gamma, const float* __restrict__ beta,
                                int N) {
    size_t i = (size_t)blockIdx.x * blockDim.x + threadIdx.x;
    size_t total = (size_t)N * 32;
    if (i >= total) return;
    int c4 = (int)(i & 31);
    float4 s = ((const float4*)stats)[c4];
    float4 q = ((const float4*)(stats + 128))[c4];
    float4 gm = ((const float4*)gamma)[c4];
    float4 bt = ((const float4*)beta)[c4];
    float inv = 1.0f / (float)N;
    float4 v = ((float4*)hbuf)[i];
    float m, var, sc;
    m = s.x * inv; var = q.x * inv - m * m; sc = gm.x * rsqrtf(var + 1e-5f); v.x = (v.x - m) * sc + bt.x;
    m = s.y * inv; var = q.y * inv - m * m; sc = gm.y * rsqrtf(var + 1e-5f); v.y = (v.y - m) * sc + bt.y;
    m = s.z * inv; var = q.z * inv - m * m; sc = gm.z * rsqrtf(var + 1e-5f); v.z = (v.z - m) * sc + bt.z;
    m = s.w * inv; var = q.w * inv - m * m; sc = gm.w * rsqrtf(var + 1e-5f); v.w = (v.w - m) * sc + bt.w;
    ((float4*)hbuf)[i] = v;
}

// ---------------- pool: batch is sorted -> per-graph contiguous range ----------------
__device__ __forceinline__ int lower_bound_i(const int* __restrict__ arr, int n, int val) {
    int lo = 0, hi = n;
    while (lo < hi) {
        int mid = (lo + hi) >> 1;
        if (arr[mid] < val) lo = mid + 1; else hi = mid;
    }
    return lo;
}

__global__ void pool_kernel(const float* __restrict__ h, const int* __restrict__ batch,
                            float* __restrict__ out, int N, int G) {
    int g = blockIdx.x;
    int lo = lower_bound_i(batch, N, g);
    int hi = lower_bound_i(batch, N, g + 1);
    int f = threadIdx.x;  // 128 threads
    float s = 0.f;
    for (int n = lo; n < hi; n++) s += h[(size_t)n * HDIM + f];
    float cnt = (float)(hi - lo);
    out[(size_t)g * HDIM + f] = s / fmaxf(cnt, 1.0f);
}

// ---------------- launch ----------------
extern "C" void kernel_launch(void* const* d_in, const int* in_sizes, int n_in,
                              void* d_out, int out_size, void* d_ws, size_t ws_size,
                              hipStream_t stream) {
    const float* x      = (const float*)d_in[0];
    const int*   ei     = (const int*)d_in[1];
    const int*   batch  = (const int*)d_in[2];
    const float* W_emb  = (const float*)d_in[3];
    const float* b_emb  = (const float*)d_in[4];
    const float* W_conv = (const float*)d_in[5];
    const float* b_conv = (const float*)d_in[6];
    const float* gamma  = (const float*)d_in[7];
    const float* beta   = (const float*)d_in[8];

    const int E = in_sizes[1] / 2;
    const int N = in_sizes[2];
    const int G = out_size / HDIM;
    const int DEPTH = 4;

    const int* srcp = ei;
    const int* dstp = ei + E;
    float* out = (float*)d_out;

    size_t NH = (size_t)N * HDIM;
    size_t npad = ((size_t)N + 63) & ~(size_t)63;
    size_t epad = ((size_t)E + 63) & ~(size_t)63;

    float* ws = (float*)d_ws;
    float* dinv   = ws;                          // npad
    int*   deg_i  = (int*)(dinv + npad);         // npad
    int*   offs   = deg_i + npad;                // npad + 64 (holds N+1)
    int*   cursor = offs + npad + 64;            // npad
    int*   csr    = cursor + npad;               // epad
    float* stats  = (float*)(csr + epad);        // 256
    float* hbuf   = stats + 256;                 // NH
    float* hws    = hbuf + NH;                   // NH

    // ---- CSR build ----
    hipMemsetAsync(deg_i, 0, npad * sizeof(int), stream);
    deg_kernel<<<1024, 256, 0, stream>>>(dstp, deg_i, E);
    dinv_kernel<<<(N + 255) / 256, 256, 0, stream>>>(deg_i, dinv, N);
    scan_kernel<<<1, 256, 0, stream>>>(deg_i, offs, N);
    hipMemsetAsync(cursor, 0, npad * sizeof(int), stream);
    fill_kernel<<<1024, 256, 0, stream>>>(srcp, dstp, offs, cursor, csr, E);

    // ---- embedding ----
    gemm128<<<(N + 63) / 64, 256, 0, stream>>>(x, W_emb, b_emb, nullptr, hbuf, N);

    int ew_blocks = (int)((NH / 4 + 255) / 256);
    int gather_blocks = (N + 3) / 4;

    for (int l = 0; l < DEPTH; l++) {
        // hws = dinv .* (h @ W)
        gemm128<<<(N + 63) / 64, 256, 0, stream>>>(hbuf, W_conv + (size_t)l * HDIM * HDIM,
                                                   nullptr, dinv, hws, N);
        gather_kernel<<<gather_blocks, 256, 0, stream>>>(hws, csr, offs, dinv,
                                                         b_conv + (size_t)l * HDIM, hbuf,
                                                         N, (l < DEPTH - 1) ? 1 : 0);
        if (l < DEPTH - 1) {
            hipMemsetAsync(stats, 0, 256 * sizeof(float), stream);
            bn_stats_kernel<<<512, 256, 0, stream>>>(hbuf, stats, N);
            bn_apply_kernel<<<ew_blocks, 256, 0, stream>>>(hbuf, stats,
                                                           gamma + (size_t)l * HDIM,
                                                           beta + (size_t)l * HDIM, N);
        }
    }

    pool_kernel<<<G, HDIM, 0, stream>>>(hbuf, batch, out, N, G);
}

// Round 4
// 637.517 us; speedup vs baseline: 2.8518x; 1.1539x over previous
//
#include <hip/hip_runtime.h>
#include <math.h>

#define HDIM 128

// ---------------- degree (int) ----------------
__global__ void deg_kernel(const int* __restrict__ dst, int* __restrict__ deg, int E) {
    int i = blockIdx.x * blockDim.x + threadIdx.x;
    int stride = gridDim.x * blockDim.x;
    for (; i < E; i += stride) atomicAdd(&deg[dst[i]], 1);
}

__global__ void dinv_kernel(const int* __restrict__ deg, float* __restrict__ dinv, int N) {
    int i = blockIdx.x * blockDim.x + threadIdx.x;
    if (i < N) dinv[i] = rsqrtf((float)deg[i] + 1.0f);
}

// ---------------- parallel scan: phase 1 — per-block (256-wide) local exclusive scan ----------------
__global__ __launch_bounds__(256) void scan_partial(const int* __restrict__ deg,
                                                    int* __restrict__ offs,
                                                    int* __restrict__ bsum, int N) {
    int i = blockIdx.x * 256 + threadIdx.x;
    int v = (i < N) ? deg[i] : 0;
    __shared__ int sm[256];
    sm[threadIdx.x] = v;
    __syncthreads();
    #pragma unroll
    for (int off = 1; off < 256; off <<= 1) {
        int t = (threadIdx.x >= off) ? sm[threadIdx.x - off] : 0;
        __syncthreads();
        sm[threadIdx.x] += t;
        __syncthreads();
    }
    if (i < N) offs[i] = sm[threadIdx.x] - v;  // local exclusive
    if (threadIdx.x == 255) bsum[blockIdx.x] = sm[255];
}

// ---------------- phase 2 — scan the (<=256) block sums, exclusive, in place ----------------
__global__ __launch_bounds__(256) void scan_bsum(int* __restrict__ bsum, int nb) {
    int v = (threadIdx.x < nb) ? bsum[threadIdx.x] : 0;
    __shared__ int sm[256];
    sm[threadIdx.x] = v;
    __syncthreads();
    #pragma unroll
    for (int off = 1; off < 256; off <<= 1) {
        int t = (threadIdx.x >= off) ? sm[threadIdx.x - off] : 0;
        __syncthreads();
        sm[threadIdx.x] += t;
        __syncthreads();
    }
    if (threadIdx.x < nb) bsum[threadIdx.x] = sm[threadIdx.x] - v;  // exclusive
}

// ---------------- phase 3 — add block prefix; offs[N] = E (known) ----------------
__global__ __launch_bounds__(256) void scan_add(const int* __restrict__ bsum,
                                                int* __restrict__ offs, int N, int E) {
    int i = blockIdx.x * 256 + threadIdx.x;
    if (i < N) offs[i] += bsum[blockIdx.x];
    if (i == 0) offs[N] = E;
}

// ---------------- CSR fill: csr_src[offs[d] + rank] = src ----------------
__global__ void fill_kernel(const int* __restrict__ src, const int* __restrict__ dst,
                            const int* __restrict__ offs, int* __restrict__ cursor,
                            int* __restrict__ csr_src, int E) {
    int i = blockIdx.x * blockDim.x + threadIdx.x;
    int stride = gridDim.x * blockDim.x;
    for (; i < E; i += stride) {
        int d = dst[i];
        int pos = atomicAdd(&cursor[d], 1);
        csr_src[offs[d] + pos] = src[i];
    }
}

// ---------------- GEMM: C[N x 128] = A[N x 128] @ B[128 x 128] (+bias) (*rowscale) ----------------
// 256 threads; tile 128 rows x 128 cols; 8 rows x 8 cols per thread.
// Inner loop: 2 ds_read_b128 per 64 FMAs -> compute-bound (was 2 per 32 = LDS-bound).
__global__ __launch_bounds__(256) void gemm128(const float* __restrict__ A,
                                               const float* __restrict__ B,
                                               const float* __restrict__ bias,
                                               const float* __restrict__ rowscale,
                                               float* __restrict__ C, int N) {
    __shared__ float Bs[128 * 128];
    {
        const float4* B4 = (const float4*)B;
        float4* Bs4 = (float4*)Bs;
        #pragma unroll
        for (int i = 0; i < 16; i++) Bs4[threadIdx.x + i * 256] = B4[threadIdx.x + i * 256];
    }
    __syncthreads();

    int tx = threadIdx.x & 15;   // col group: cols tx*8 .. tx*8+7
    int ty = threadIdx.x >> 4;   // row group: rows ty*8 .. ty*8+7
    int row0 = blockIdx.x * 128 + ty * 8;
    int col0 = tx * 8;

    float4 acc[8][2];
    float4 bz0 = make_float4(0.f, 0.f, 0.f, 0.f), bz1 = bz0;
    if (bias) {
        bz0 = *(const float4*)(bias + col0);
        bz1 = *(const float4*)(bias + col0 + 4);
    }
    #pragma unroll
    for (int i = 0; i < 8; i++) { acc[i][0] = bz0; acc[i][1] = bz1; }

    int r[8];
    #pragma unroll
    for (int i = 0; i < 8; i++) r[i] = min(row0 + i, N - 1);

    for (int k = 0; k < 128; k += 4) {
        float4 a[8];
        #pragma unroll
        for (int i = 0; i < 8; i++) a[i] = *(const float4*)(A + (size_t)r[i] * 128 + k);
        #pragma unroll
        for (int kk = 0; kk < 4; kk++) {
            float4 b0 = *(const float4*)(&Bs[(k + kk) * 128 + col0]);
            float4 b1 = *(const float4*)(&Bs[(k + kk) * 128 + col0 + 4]);
            #pragma unroll
            for (int i = 0; i < 8; i++) {
                float av = (kk == 0) ? a[i].x : (kk == 1) ? a[i].y : (kk == 2) ? a[i].z : a[i].w;
                acc[i][0].x += av * b0.x; acc[i][0].y += av * b0.y;
                acc[i][0].z += av * b0.z; acc[i][0].w += av * b0.w;
                acc[i][1].x += av * b1.x; acc[i][1].y += av * b1.y;
                acc[i][1].z += av * b1.z; acc[i][1].w += av * b1.w;
            }
        }
    }

    #pragma unroll
    for (int i = 0; i < 8; i++) {
        int rr = row0 + i;
        if (rr < N) {
            float sc = rowscale ? rowscale[rr] : 1.0f;
            float4 o0 = acc[i][0], o1 = acc[i][1];
            o0.x *= sc; o0.y *= sc; o0.z *= sc; o0.w *= sc;
            o1.x *= sc; o1.y *= sc; o1.z *= sc; o1.w *= sc;
            *(float4*)(C + (size_t)rr * 128 + col0) = o0;
            *(float4*)(C + (size_t)rr * 128 + col0 + 4) = o1;
        }
    }
}

// ---------------- gather: out[d] = dinv[d]*(sum_{s in in(d)} hws[s] + hws[d]) + bias ----------------
__global__ __launch_bounds__(256) void gather_kernel(const float* __restrict__ hws,
                                                     const int* __restrict__ csr_src,
                                                     const int* __restrict__ offs,
                                                     const float* __restrict__ dinv,
                                                     const float* __restrict__ bias,
                                                     float* __restrict__ out,
                                                     int N, int relu) {
    int lane = threadIdx.x & 63;
    int node = blockIdx.x * 4 + (threadIdx.x >> 6);
    if (node >= N) return;
    int lo = offs[node], hi = offs[node + 1];

    float2 acc = make_float2(0.f, 0.f);
    int j = lo;
    for (; j + 3 < hi; j += 4) {
        int s0 = csr_src[j], s1 = csr_src[j + 1], s2 = csr_src[j + 2], s3 = csr_src[j + 3];
        float2 v0 = ((const float2*)(hws + (size_t)s0 * HDIM))[lane];
        float2 v1 = ((const float2*)(hws + (size_t)s1 * HDIM))[lane];
        float2 v2 = ((const float2*)(hws + (size_t)s2 * HDIM))[lane];
        float2 v3 = ((const float2*)(hws + (size_t)s3 * HDIM))[lane];
        acc.x += v0.x + v1.x + v2.x + v3.x;
        acc.y += v0.y + v1.y + v2.y + v3.y;
    }
    for (; j < hi; j++) {
        int s = csr_src[j];
        float2 v = ((const float2*)(hws + (size_t)s * HDIM))[lane];
        acc.x += v.x; acc.y += v.y;
    }
    float2 vs = ((const float2*)(hws + (size_t)node * HDIM))[lane];
    float di = dinv[node];
    float2 b = ((const float2*)bias)[lane];
    float ox = di * (acc.x + vs.x) + b.x;
    float oy = di * (acc.y + vs.y) + b.y;
    if (relu) { ox = fmaxf(ox, 0.f); oy = fmaxf(oy, 0.f); }
    ((float2*)(out + (size_t)node * HDIM))[lane] = make_float2(ox, oy);
}

// ---------------- batchnorm stats: per-feature sum & sumsq ----------------
__global__ __launch_bounds__(256) void bn_stats_kernel(const float* __restrict__ h,
                                                       float* __restrict__ stats, int N) {
    int f = threadIdx.x & 127;
    int half = threadIdx.x >> 7;  // 0..1
    float s = 0.f, s2 = 0.f;
    for (int n = blockIdx.x * 2 + half; n < N; n += gridDim.x * 2) {
        float v = h[(size_t)n * HDIM + f];
        s += v;
        s2 += v * v;
    }
    __shared__ float ls[256], ls2[256];
    ls[threadIdx.x] = s;
    ls2[threadIdx.x] = s2;
    __syncthreads();
    if (half == 0) {
        s = ls[f] + ls[f + 128];
        s2 = ls2[f] + ls2[f + 128];
        atomicAdd(&stats[f], s);
        atomicAdd(&stats[128 + f], s2);
    }
}

__global__ void bn_apply_kernel(float* __restrict__ hbuf, const float* __restrict__ stats,
                                const float* __restrict__ gamma, const float* __restrict__ beta,
                                int N) {
    size_t i = (size_t)blockIdx.x * blockDim.x + threadIdx.x;
    size_t total = (size_t)N * 32;
    if (i >= total) return;
    int c4 = (int)(i & 31);
    float4 s = ((const float4*)stats)[c4];
    float4 q = ((const float4*)(stats + 128))[c4];
    float4 gm = ((const float4*)gamma)[c4];
    float4 bt = ((const float4*)beta)[c4];
    float inv = 1.0f / (float)N;
    float4 v = ((float4*)hbuf)[i];
    float m, var, sc;
    m = s.x * inv; var = q.x * inv - m * m; sc = gm.x * rsqrtf(var + 1e-5f); v.x = (v.x - m) * sc + bt.x;
    m = s.y * inv; var = q.y * inv - m * m; sc = gm.y * rsqrtf(var + 1e-5f); v.y = (v.y - m) * sc + bt.y;
    m = s.z * inv; var = q.z * inv - m * m; sc = gm.z * rsqrtf(var + 1e-5f); v.z = (v.z - m) * sc + bt.z;
    m = s.w * inv; var = q.w * inv - m * m; sc = gm.w * rsqrtf(var + 1e-5f); v.w = (v.w - m) * sc + bt.w;
    ((float4*)hbuf)[i] = v;
}

// ---------------- pool: batch is sorted -> per-graph contiguous range ----------------
__device__ __forceinline__ int lower_bound_i(const int* __restrict__ arr, int n, int val) {
    int lo = 0, hi = n;
    while (lo < hi) {
        int mid = (lo + hi) >> 1;
        if (arr[mid] < val) lo = mid + 1; else hi = mid;
    }
    return lo;
}

__global__ void pool_kernel(const float* __restrict__ h, const int* __restrict__ batch,
                            float* __restrict__ out, int N, int G) {
    int g = blockIdx.x;
    int lo = lower_bound_i(batch, N, g);
    int hi = lower_bound_i(batch, N, g + 1);
    int f = threadIdx.x;  // 128 threads
    float s = 0.f;
    for (int n = lo; n < hi; n++) s += h[(size_t)n * HDIM + f];
    float cnt = (float)(hi - lo);
    out[(size_t)g * HDIM + f] = s / fmaxf(cnt, 1.0f);
}

// ---------------- launch ----------------
extern "C" void kernel_launch(void* const* d_in, const int* in_sizes, int n_in,
                              void* d_out, int out_size, void* d_ws, size_t ws_size,
                              hipStream_t stream) {
    const float* x      = (const float*)d_in[0];
    const int*   ei     = (const int*)d_in[1];
    const int*   batch  = (const int*)d_in[2];
    const float* W_emb  = (const float*)d_in[3];
    const float* b_emb  = (const float*)d_in[4];
    const float* W_conv = (const float*)d_in[5];
    const float* b_conv = (const float*)d_in[6];
    const float* gamma  = (const float*)d_in[7];
    const float* beta   = (const float*)d_in[8];

    const int E = in_sizes[1] / 2;
    const int N = in_sizes[2];
    const int G = out_size / HDIM;
    const int DEPTH = 4;

    const int* srcp = ei;
    const int* dstp = ei + E;
    float* out = (float*)d_out;

    size_t NH = (size_t)N * HDIM;
    size_t npad = ((size_t)N + 63) & ~(size_t)63;
    size_t epad = ((size_t)E + 63) & ~(size_t)63;
    int NB = (N + 255) / 256;  // blocks for scan (must be <= 256)

    float* ws = (float*)d_ws;
    float* dinv   = ws;                          // npad
    int*   deg_i  = (int*)(dinv + npad);         // npad
    int*   offs   = deg_i + npad;                // npad + 64 (holds N+1)
    int*   cursor = offs + npad + 64;            // npad
    int*   bsum   = cursor + npad;               // 256
    int*   csr    = bsum + 256;                  // epad
    float* stats  = (float*)(csr + epad);        // 256
    float* hbuf   = stats + 256;                 // NH
    float* hws    = hbuf + NH;                   // NH

    // ---- CSR build ----
    hipMemsetAsync(deg_i, 0, npad * sizeof(int), stream);
    deg_kernel<<<1024, 256, 0, stream>>>(dstp, deg_i, E);
    dinv_kernel<<<(N + 255) / 256, 256, 0, stream>>>(deg_i, dinv, N);
    scan_partial<<<NB, 256, 0, stream>>>(deg_i, offs, bsum, N);
    scan_bsum<<<1, 256, 0, stream>>>(bsum, NB);
    scan_add<<<NB, 256, 0, stream>>>(bsum, offs, N, E);
    hipMemsetAsync(cursor, 0, npad * sizeof(int), stream);
    fill_kernel<<<1024, 256, 0, stream>>>(srcp, dstp, offs, cursor, csr, E);

    // ---- embedding ----
    gemm128<<<(N + 127) / 128, 256, 0, stream>>>(x, W_emb, b_emb, nullptr, hbuf, N);

    int ew_blocks = (int)((NH / 4 + 255) / 256);
    int gather_blocks = (N + 3) / 4;

    for (int l = 0; l < DEPTH; l++) {
        gemm128<<<(N + 127) / 128, 256, 0, stream>>>(hbuf, W_conv + (size_t)l * HDIM * HDIM,
                                                     nullptr, dinv, hws, N);
        gather_kernel<<<gather_blocks, 256, 0, stream>>>(hws, csr, offs, dinv,
                                                         b_conv + (size_t)l * HDIM, hbuf,
                                                         N, (l < DEPTH - 1) ? 1 : 0);
        if (l < DEPTH - 1) {
            hipMemsetAsync(stats, 0, 256 * sizeof(float), stream);
            bn_stats_kernel<<<512, 256, 0, stream>>>(hbuf, stats, N);
            bn_apply_kernel<<<ew_blocks, 256, 0, stream>>>(hbuf, stats,
                                                           gamma + (size_t)l * HDIM,
                                                           beta + (size_t)l * HDIM, N);
        }
    }

    pool_kernel<<<G, HDIM, 0, stream>>>(hbuf, batch, out, N, G);
}

// Round 5
// 579.151 us; speedup vs baseline: 3.1392x; 1.1008x over previous
//
#include <hip/hip_runtime.h>
#include <math.h>

#define HDIM 128

typedef __attribute__((ext_vector_type(8))) short bf16x8;
typedef __attribute__((ext_vector_type(4))) float f32x4;

union U4 { unsigned int u[4]; bf16x8 v; };

__device__ __forceinline__ unsigned int cvt_pk_bf16(float a, float b) {
    unsigned int r;
    asm("v_cvt_pk_bf16_f32 %0, %1, %2" : "=v"(r) : "v"(a), "v"(b));
    return r;
}

// split 8 fp32 -> hi bf16x8 + lo bf16x8 (x ~= hi + lo, error ~2^-17 |x|)
__device__ __forceinline__ void split8(const float* v, bf16x8& ah, bf16x8& al) {
    U4 H, L;
    #pragma unroll
    for (int p = 0; p < 4; p++) {
        unsigned int h = cvt_pk_bf16(v[2 * p], v[2 * p + 1]);
        H.u[p] = h;
        float h0 = __uint_as_float(h << 16);
        float h1 = __uint_as_float(h & 0xFFFF0000u);
        L.u[p] = cvt_pk_bf16(v[2 * p] - h0, v[2 * p + 1] - h1);
    }
    ah = H.v; al = L.v;
}

// ---------------- degree (int) ----------------
__global__ void deg_kernel(const int* __restrict__ dst, int* __restrict__ deg, int E) {
    int i = blockIdx.x * blockDim.x + threadIdx.x;
    int stride = gridDim.x * blockDim.x;
    for (; i < E; i += stride) atomicAdd(&deg[dst[i]], 1);
}

__global__ void dinv_kernel(const int* __restrict__ deg, float* __restrict__ dinv, int N) {
    int i = blockIdx.x * blockDim.x + threadIdx.x;
    if (i < N) dinv[i] = rsqrtf((float)deg[i] + 1.0f);
}

// ---------------- parallel scan ----------------
__global__ __launch_bounds__(256) void scan_partial(const int* __restrict__ deg,
                                                    int* __restrict__ offs,
                                                    int* __restrict__ bsum, int N) {
    int i = blockIdx.x * 256 + threadIdx.x;
    int v = (i < N) ? deg[i] : 0;
    __shared__ int sm[256];
    sm[threadIdx.x] = v;
    __syncthreads();
    #pragma unroll
    for (int off = 1; off < 256; off <<= 1) {
        int t = (threadIdx.x >= off) ? sm[threadIdx.x - off] : 0;
        __syncthreads();
        sm[threadIdx.x] += t;
        __syncthreads();
    }
    if (i < N) offs[i] = sm[threadIdx.x] - v;
    if (threadIdx.x == 255) bsum[blockIdx.x] = sm[255];
}

__global__ __launch_bounds__(256) void scan_bsum(int* __restrict__ bsum, int nb) {
    int v = (threadIdx.x < nb) ? bsum[threadIdx.x] : 0;
    __shared__ int sm[256];
    sm[threadIdx.x] = v;
    __syncthreads();
    #pragma unroll
    for (int off = 1; off < 256; off <<= 1) {
        int t = (threadIdx.x >= off) ? sm[threadIdx.x - off] : 0;
        __syncthreads();
        sm[threadIdx.x] += t;
        __syncthreads();
    }
    if (threadIdx.x < nb) bsum[threadIdx.x] = sm[threadIdx.x] - v;
}

__global__ __launch_bounds__(256) void scan_add(const int* __restrict__ bsum,
                                                int* __restrict__ offs, int N, int E) {
    int i = blockIdx.x * 256 + threadIdx.x;
    if (i < N) offs[i] += bsum[blockIdx.x];
    if (i == 0) offs[N] = E;
}

// ---------------- CSR fill ----------------
__global__ void fill_kernel(const int* __restrict__ src, const int* __restrict__ dst,
                            const int* __restrict__ offs, int* __restrict__ cursor,
                            int* __restrict__ csr_src, int E) {
    int i = blockIdx.x * blockDim.x + threadIdx.x;
    int stride = gridDim.x * blockDim.x;
    for (; i < E; i += stride) {
        int d = dst[i];
        int pos = atomicAdd(&cursor[d], 1);
        csr_src[offs[d] + pos] = src[i];
    }
}

// ---------------- weight split: W[k][n] fp32 -> Wh/Wl[n][k] bf16 (RNE) ----------------
__global__ void wsplit_kernel(const float* __restrict__ Wsrc, short* __restrict__ Whi,
                              short* __restrict__ Wlo) {
    int i = blockIdx.x * 256 + threadIdx.x;   // i = n*128 + k
    if (i >= 128 * 128) return;
    int n = i >> 7, k = i & 127;
    float v = Wsrc[k * 128 + n];
    unsigned int u = __float_as_uint(v);
    unsigned int hi = (u + 0x7FFFu + ((u >> 16) & 1)) & 0xFFFF0000u;
    float hf = __uint_as_float(hi);
    float lo = v - hf;
    unsigned int ul = __float_as_uint(lo);
    unsigned int lo16 = (ul + 0x7FFFu + ((ul >> 16) & 1)) >> 16;
    Whi[i] = (short)(hi >> 16);
    Wlo[i] = (short)lo16;
}

// ---------------- MFMA GEMM: C[N x 128] = affine(A)[N x 128] @ W[128 x 128] ----------------
// 256 thr = 4 waves; block tile 128x128; wave tile 64x64 (4x4 MFMA 16x16x32 tiles).
// Split-bf16 3-product: D += Ah*Bh + Ah*Bl + Al*Bh  (~fp32 precision).
// Optional: per-feature affine on A (fused BN apply), bias (per col), rowscale (per row).
__global__ __launch_bounds__(256) void gemm_mfma(const float* __restrict__ A,
                                                 const short* __restrict__ Wh,
                                                 const short* __restrict__ Wl,
                                                 const float* __restrict__ aff_s,
                                                 const float* __restrict__ aff_t,
                                                 const float* __restrict__ bias,
                                                 const float* __restrict__ rowscale,
                                                 float* __restrict__ outf, int N) {
    int w = threadIdx.x >> 6;
    int lane = threadIdx.x & 63;
    int l15 = lane & 15, lg = lane >> 4;
    int r0 = blockIdx.x * 128 + (w >> 1) * 64;
    int c0 = (w & 1) * 64;

    f32x4 acc[4][4];
    #pragma unroll
    for (int tc = 0; tc < 4; tc++) {
        float bz = bias ? bias[c0 + tc * 16 + l15] : 0.0f;
        #pragma unroll
        for (int tr = 0; tr < 4; tr++) {
            acc[tr][tc][0] = bz; acc[tr][tc][1] = bz;
            acc[tr][tc][2] = bz; acc[tr][tc][3] = bz;
        }
    }

    #pragma unroll
    for (int kt = 0; kt < 4; kt++) {
        int kk = kt * 32 + lg * 8;   // this lane's k base

        bf16x8 bh[4], bl[4];
        #pragma unroll
        for (int tc = 0; tc < 4; tc++) {
            int n = c0 + tc * 16 + l15;
            bh[tc] = *(const bf16x8*)(Wh + n * 128 + kk);
            bl[tc] = *(const bf16x8*)(Wl + n * 128 + kk);
        }

        float sv[8], tv[8];
        if (aff_s) {
            *(float4*)&sv[0] = *(const float4*)(aff_s + kk);
            *(float4*)&sv[4] = *(const float4*)(aff_s + kk + 4);
            *(float4*)&tv[0] = *(const float4*)(aff_t + kk);
            *(float4*)&tv[4] = *(const float4*)(aff_t + kk + 4);
        }

        bf16x8 ah[4], al[4];
        #pragma unroll
        for (int tr = 0; tr < 4; tr++) {
            int row = min(r0 + tr * 16 + l15, N - 1);
            const float* ap = A + (size_t)row * 128 + kk;
            float v[8];
            *(float4*)&v[0] = *(const float4*)ap;
            *(float4*)&v[4] = *(const float4*)(ap + 4);
            if (aff_s) {
                #pragma unroll
                for (int j = 0; j < 8; j++) v[j] = fmaf(v[j], sv[j], tv[j]);
            }
            split8(v, ah[tr], al[tr]);
        }

        #pragma unroll
        for (int tr = 0; tr < 4; tr++) {
            #pragma unroll
            for (int tc = 0; tc < 4; tc++) {
                acc[tr][tc] = __builtin_amdgcn_mfma_f32_16x16x32_bf16(ah[tr], bh[tc], acc[tr][tc], 0, 0, 0);
                acc[tr][tc] = __builtin_amdgcn_mfma_f32_16x16x32_bf16(ah[tr], bl[tc], acc[tr][tc], 0, 0, 0);
                acc[tr][tc] = __builtin_amdgcn_mfma_f32_16x16x32_bf16(al[tr], bh[tc], acc[tr][tc], 0, 0, 0);
            }
        }
    }

    // C/D layout: row = (lane>>4)*4 + reg, col = lane&15 (per 16x16 tile)
    #pragma unroll
    for (int tr = 0; tr < 4; tr++) {
        #pragma unroll
        for (int r = 0; r < 4; r++) {
            int row = r0 + tr * 16 + lg * 4 + r;
            if (row < N) {
                float sc = rowscale ? rowscale[row] : 1.0f;
                #pragma unroll
                for (int tc = 0; tc < 4; tc++) {
                    int col = c0 + tc * 16 + l15;
                    outf[(size_t)row * 128 + col] = acc[tr][tc][r] * sc;
                }
            }
        }
    }
}

// ---------------- gather: out[d] = dinv[d]*(sum_{s in in(d)} hws[s] + hws[d]) + bias ----------------
__global__ __launch_bounds__(256) void gather_kernel(const float* __restrict__ hws,
                                                     const int* __restrict__ csr_src,
                                                     const int* __restrict__ offs,
                                                     const float* __restrict__ dinv,
                                                     const float* __restrict__ bias,
                                                     float* __restrict__ out,
                                                     int N, int relu) {
    int lane = threadIdx.x & 63;
    int node = blockIdx.x * 4 + (threadIdx.x >> 6);
    if (node >= N) return;
    int lo = offs[node], hi = offs[node + 1];

    float2 acc = make_float2(0.f, 0.f);
    int j = lo;
    for (; j + 3 < hi; j += 4) {
        int s0 = csr_src[j], s1 = csr_src[j + 1], s2 = csr_src[j + 2], s3 = csr_src[j + 3];
        float2 v0 = ((const float2*)(hws + (size_t)s0 * HDIM))[lane];
        float2 v1 = ((const float2*)(hws + (size_t)s1 * HDIM))[lane];
        float2 v2 = ((const float2*)(hws + (size_t)s2 * HDIM))[lane];
        float2 v3 = ((const float2*)(hws + (size_t)s3 * HDIM))[lane];
        acc.x += v0.x + v1.x + v2.x + v3.x;
        acc.y += v0.y + v1.y + v2.y + v3.y;
    }
    for (; j < hi; j++) {
        int s = csr_src[j];
        float2 v = ((const float2*)(hws + (size_t)s * HDIM))[lane];
        acc.x += v.x; acc.y += v.y;
    }
    float2 vs = ((const float2*)(hws + (size_t)node * HDIM))[lane];
    float di = dinv[node];
    float2 b = ((const float2*)bias)[lane];
    float ox = di * (acc.x + vs.x) + b.x;
    float oy = di * (acc.y + vs.y) + b.y;
    if (relu) { ox = fmaxf(ox, 0.f); oy = fmaxf(oy, 0.f); }
    ((float2*)(out + (size_t)node * HDIM))[lane] = make_float2(ox, oy);
}

// ---------------- batchnorm stats: per-feature sum & sumsq ----------------
__global__ __launch_bounds__(256) void bn_stats_kernel(const float* __restrict__ h,
                                                       float* __restrict__ stats, int N) {
    int f = threadIdx.x & 127;
    int half = threadIdx.x >> 7;
    float s = 0.f, s2 = 0.f;
    for (int n = blockIdx.x * 2 + half; n < N; n += gridDim.x * 2) {
        float v = h[(size_t)n * HDIM + f];
        s += v;
        s2 += v * v;
    }
    __shared__ float ls[256], ls2[256];
    ls[threadIdx.x] = s;
    ls2[threadIdx.x] = s2;
    __syncthreads();
    if (half == 0) {
        s = ls[f] + ls[f + 128];
        s2 = ls2[f] + ls2[f + 128];
        atomicAdd(&stats[f], s);
        atomicAdd(&stats[128 + f], s2);
    }
}

// ---------------- bn finalize: s = g*rsqrt(var+eps), t = b - m*s ----------------
__global__ void bn_finalize(const float* __restrict__ stats, const float* __restrict__ gamma,
                            const float* __restrict__ beta, float* __restrict__ aff_s,
                            float* __restrict__ aff_t, int N) {
    int f = threadIdx.x;  // 128
    float inv = 1.0f / (float)N;
    float m = stats[f] * inv;
    float var = stats[128 + f] * inv - m * m;
    float s = gamma[f] * rsqrtf(var + 1e-5f);
    aff_s[f] = s;
    aff_t[f] = beta[f] - m * s;
}

// ---------------- pool ----------------
__device__ __forceinline__ int lower_bound_i(const int* __restrict__ arr, int n, int val) {
    int lo = 0, hi = n;
    while (lo < hi) {
        int mid = (lo + hi) >> 1;
        if (arr[mid] < val) lo = mid + 1; else hi = mid;
    }
    return lo;
}

__global__ void pool_kernel(const float* __restrict__ h, const int* __restrict__ batch,
                            float* __restrict__ out, int N, int G) {
    int g = blockIdx.x;
    int lo = lower_bound_i(batch, N, g);
    int hi = lower_bound_i(batch, N, g + 1);
    int f = threadIdx.x;
    float s = 0.f;
    for (int n = lo; n < hi; n++) s += h[(size_t)n * HDIM + f];
    float cnt = (float)(hi - lo);
    out[(size_t)g * HDIM + f] = s / fmaxf(cnt, 1.0f);
}

// ---------------- launch ----------------
extern "C" void kernel_launch(void* const* d_in, const int* in_sizes, int n_in,
                              void* d_out, int out_size, void* d_ws, size_t ws_size,
                              hipStream_t stream) {
    const float* x      = (const float*)d_in[0];
    const int*   ei     = (const int*)d_in[1];
    const int*   batch  = (const int*)d_in[2];
    const float* W_emb  = (const float*)d_in[3];
    const float* b_emb  = (const float*)d_in[4];
    const float* W_conv = (const float*)d_in[5];
    const float* b_conv = (const float*)d_in[6];
    const float* gamma  = (const float*)d_in[7];
    const float* beta   = (const float*)d_in[8];

    const int E = in_sizes[1] / 2;
    const int N = in_sizes[2];
    const int G = out_size / HDIM;
    const int DEPTH = 4;

    const int* srcp = ei;
    const int* dstp = ei + E;
    float* out = (float*)d_out;

    size_t NH = (size_t)N * HDIM;
    size_t npad = ((size_t)N + 63) & ~(size_t)63;
    size_t epad = ((size_t)E + 63) & ~(size_t)63;
    int NB = (N + 255) / 256;

    float* ws = (float*)d_ws;
    float* dinv   = ws;                          // npad
    int*   deg_i  = (int*)(dinv + npad);         // npad
    int*   offs   = deg_i + npad;                // npad + 64
    int*   cursor = offs + npad + 64;            // npad
    int*   bsum   = cursor + npad;               // 256
    int*   csr    = bsum + 256;                  // epad
    float* stats  = (float*)(csr + epad);        // 256
    float* aff_s  = stats + 256;                 // 128
    float* aff_t  = aff_s + 128;                 // 128
    short* wt     = (short*)(aff_t + 128);       // 5 * 2 * 16384 shorts
    float* hbuf   = (float*)(wt + 5 * 2 * 16384);// NH
    float* hws    = hbuf + NH;                   // NH

    // ---- weight split (5 matrices: emb + 4 conv) ----
    wsplit_kernel<<<64, 256, 0, stream>>>(W_emb, wt, wt + 16384);
    for (int l = 0; l < DEPTH; l++) {
        short* whi = wt + (size_t)(l + 1) * 32768;
        wsplit_kernel<<<64, 256, 0, stream>>>(W_conv + (size_t)l * 16384, whi, whi + 16384);
    }

    // ---- CSR build ----
    hipMemsetAsync(deg_i, 0, npad * sizeof(int), stream);
    deg_kernel<<<1024, 256, 0, stream>>>(dstp, deg_i, E);
    dinv_kernel<<<(N + 255) / 256, 256, 0, stream>>>(deg_i, dinv, N);
    scan_partial<<<NB, 256, 0, stream>>>(deg_i, offs, bsum, N);
    scan_bsum<<<1, 256, 0, stream>>>(bsum, NB);
    scan_add<<<NB, 256, 0, stream>>>(bsum, offs, N, E);
    hipMemsetAsync(cursor, 0, npad * sizeof(int), stream);
    fill_kernel<<<1024, 256, 0, stream>>>(srcp, dstp, offs, cursor, csr, E);

    int gemm_blocks = (N + 127) / 128;

    // ---- embedding: hbuf = x @ W_emb + b_emb ----
    gemm_mfma<<<gemm_blocks, 256, 0, stream>>>(x, wt, wt + 16384, nullptr, nullptr,
                                               b_emb, nullptr, hbuf, N);

    int gather_blocks = (N + 3) / 4;

    for (int l = 0; l < DEPTH; l++) {
        short* whi = wt + (size_t)(l + 1) * 32768;
        // hws = dinv .* (BN_affine(hbuf) @ W_conv[l])   (affine only for l>0)
        gemm_mfma<<<gemm_blocks, 256, 0, stream>>>(hbuf, whi, whi + 16384,
                                                   (l > 0) ? aff_s : nullptr,
                                                   (l > 0) ? aff_t : nullptr,
                                                   nullptr, dinv, hws, N);
        gather_kernel<<<gather_blocks, 256, 0, stream>>>(hws, csr, offs, dinv,
                                                         b_conv + (size_t)l * HDIM, hbuf,
                                                         N, (l < DEPTH - 1) ? 1 : 0);
        if (l < DEPTH - 1) {
            hipMemsetAsync(stats, 0, 256 * sizeof(float), stream);
            bn_stats_kernel<<<512, 256, 0, stream>>>(hbuf, stats, N);
            bn_finalize<<<1, 128, 0, stream>>>(stats, gamma + (size_t)l * HDIM,
                                               beta + (size_t)l * HDIM, aff_s, aff_t, N);
        }
    }

    pool_kernel<<<G, HDIM, 0, stream>>>(hbuf, batch, out, N, G);
}

// Round 6
// 497.704 us; speedup vs baseline: 3.6529x; 1.1636x over previous
//
#include <hip/hip_runtime.h>
#include <hip/hip_fp16.h>
#include <math.h>

#define HDIM 128

typedef __attribute__((ext_vector_type(8))) short bf16x8;
typedef __attribute__((ext_vector_type(4))) float f32x4;

union U4 { unsigned int u[4]; bf16x8 v; };

__device__ __forceinline__ unsigned int cvt_pk_bf16(float a, float b) {
    unsigned int r;
    asm("v_cvt_pk_bf16_f32 %0, %1, %2" : "=v"(r) : "v"(a), "v"(b));
    return r;
}

// split 8 fp32 -> hi bf16x8 + lo bf16x8 (x ~= hi + lo, error ~2^-17 |x|)
__device__ __forceinline__ void split8(const float* v, bf16x8& ah, bf16x8& al) {
    U4 H, L;
    #pragma unroll
    for (int p = 0; p < 4; p++) {
        unsigned int h = cvt_pk_bf16(v[2 * p], v[2 * p + 1]);
        H.u[p] = h;
        float h0 = __uint_as_float(h << 16);
        float h1 = __uint_as_float(h & 0xFFFF0000u);
        L.u[p] = cvt_pk_bf16(v[2 * p] - h0, v[2 * p + 1] - h1);
    }
    ah = H.v; al = L.v;
}

// ---------------- degree (int) ----------------
__global__ void deg_kernel(const int* __restrict__ dst, int* __restrict__ deg, int E) {
    int i = blockIdx.x * blockDim.x + threadIdx.x;
    int stride = gridDim.x * blockDim.x;
    for (; i < E; i += stride) atomicAdd(&deg[dst[i]], 1);
}

__global__ void dinv_kernel(const int* __restrict__ deg, float* __restrict__ dinv, int N) {
    int i = blockIdx.x * blockDim.x + threadIdx.x;
    if (i < N) dinv[i] = rsqrtf((float)deg[i] + 1.0f);
}

// ---------------- parallel scan ----------------
__global__ __launch_bounds__(256) void scan_partial(const int* __restrict__ deg,
                                                    int* __restrict__ offs,
                                                    int* __restrict__ bsum, int N) {
    int i = blockIdx.x * 256 + threadIdx.x;
    int v = (i < N) ? deg[i] : 0;
    __shared__ int sm[256];
    sm[threadIdx.x] = v;
    __syncthreads();
    #pragma unroll
    for (int off = 1; off < 256; off <<= 1) {
        int t = (threadIdx.x >= off) ? sm[threadIdx.x - off] : 0;
        __syncthreads();
        sm[threadIdx.x] += t;
        __syncthreads();
    }
    if (i < N) offs[i] = sm[threadIdx.x] - v;
    if (threadIdx.x == 255) bsum[blockIdx.x] = sm[255];
}

__global__ __launch_bounds__(256) void scan_bsum(int* __restrict__ bsum, int nb) {
    int v = (threadIdx.x < nb) ? bsum[threadIdx.x] : 0;
    __shared__ int sm[256];
    sm[threadIdx.x] = v;
    __syncthreads();
    #pragma unroll
    for (int off = 1; off < 256; off <<= 1) {
        int t = (threadIdx.x >= off) ? sm[threadIdx.x - off] : 0;
        __syncthreads();
        sm[threadIdx.x] += t;
        __syncthreads();
    }
    if (threadIdx.x < nb) bsum[threadIdx.x] = sm[threadIdx.x] - v;
}

__global__ __launch_bounds__(256) void scan_add(const int* __restrict__ bsum,
                                                int* __restrict__ offs, int N, int E) {
    int i = blockIdx.x * 256 + threadIdx.x;
    if (i < N) offs[i] += bsum[blockIdx.x];
    if (i == 0) offs[N] = E;
}

// ---------------- CSR fill ----------------
__global__ void fill_kernel(const int* __restrict__ src, const int* __restrict__ dst,
                            const int* __restrict__ offs, int* __restrict__ cursor,
                            int* __restrict__ csr_src, int E) {
    int i = blockIdx.x * blockDim.x + threadIdx.x;
    int stride = gridDim.x * blockDim.x;
    for (; i < E; i += stride) {
        int d = dst[i];
        int pos = atomicAdd(&cursor[d], 1);
        csr_src[offs[d] + pos] = src[i];
    }
}

// ---------------- weight split: W[k][n] fp32 -> Wh/Wl[n][k] bf16 (RNE) ----------------
__global__ void wsplit_kernel(const float* __restrict__ Wsrc, short* __restrict__ Whi,
                              short* __restrict__ Wlo) {
    int i = blockIdx.x * 256 + threadIdx.x;   // i = n*128 + k
    if (i >= 128 * 128) return;
    int n = i >> 7, k = i & 127;
    float v = Wsrc[k * 128 + n];
    unsigned int u = __float_as_uint(v);
    unsigned int hi = (u + 0x7FFFu + ((u >> 16) & 1)) & 0xFFFF0000u;
    float hf = __uint_as_float(hi);
    float lo = v - hf;
    unsigned int ul = __float_as_uint(lo);
    unsigned int lo16 = (ul + 0x7FFFu + ((ul >> 16) & 1)) >> 16;
    Whi[i] = (short)(hi >> 16);
    Wlo[i] = (short)lo16;
}

// ---------------- MFMA GEMM: C[N x 128] = affine(A)[N x 128] @ W[128 x 128] ----------------
// 256 thr = 4 waves; block tile 128x128; wave tile 64x64 (4x4 MFMA 16x16x32 tiles).
// Split-bf16 3-product: D += Ah*Bh + Ah*Bl + Al*Bh  (~fp32 precision).
// OUT_F16: write fp16 (pre-aggregation intermediate); else fp32.
template <bool OUT_F16>
__global__ __launch_bounds__(256) void gemm_mfma(const float* __restrict__ A,
                                                 const short* __restrict__ Wh,
                                                 const short* __restrict__ Wl,
                                                 const float* __restrict__ aff_s,
                                                 const float* __restrict__ aff_t,
                                                 const float* __restrict__ bias,
                                                 const float* __restrict__ rowscale,
                                                 void* __restrict__ outp, int N) {
    int w = threadIdx.x >> 6;
    int lane = threadIdx.x & 63;
    int l15 = lane & 15, lg = lane >> 4;
    int r0 = blockIdx.x * 128 + (w >> 1) * 64;
    int c0 = (w & 1) * 64;

    f32x4 acc[4][4];
    #pragma unroll
    for (int tc = 0; tc < 4; tc++) {
        float bz = bias ? bias[c0 + tc * 16 + l15] : 0.0f;
        #pragma unroll
        for (int tr = 0; tr < 4; tr++) {
            acc[tr][tc][0] = bz; acc[tr][tc][1] = bz;
            acc[tr][tc][2] = bz; acc[tr][tc][3] = bz;
        }
    }

    #pragma unroll
    for (int kt = 0; kt < 4; kt++) {
        int kk = kt * 32 + lg * 8;   // this lane's k base

        bf16x8 bh[4], bl[4];
        #pragma unroll
        for (int tc = 0; tc < 4; tc++) {
            int n = c0 + tc * 16 + l15;
            bh[tc] = *(const bf16x8*)(Wh + n * 128 + kk);
            bl[tc] = *(const bf16x8*)(Wl + n * 128 + kk);
        }

        float sv[8], tv[8];
        if (aff_s) {
            *(float4*)&sv[0] = *(const float4*)(aff_s + kk);
            *(float4*)&sv[4] = *(const float4*)(aff_s + kk + 4);
            *(float4*)&tv[0] = *(const float4*)(aff_t + kk);
            *(float4*)&tv[4] = *(const float4*)(aff_t + kk + 4);
        }

        bf16x8 ah[4], al[4];
        #pragma unroll
        for (int tr = 0; tr < 4; tr++) {
            int row = min(r0 + tr * 16 + l15, N - 1);
            const float* ap = A + (size_t)row * 128 + kk;
            float v[8];
            *(float4*)&v[0] = *(const float4*)ap;
            *(float4*)&v[4] = *(const float4*)(ap + 4);
            if (aff_s) {
                #pragma unroll
                for (int j = 0; j < 8; j++) v[j] = fmaf(v[j], sv[j], tv[j]);
            }
            split8(v, ah[tr], al[tr]);
        }

        #pragma unroll
        for (int tr = 0; tr < 4; tr++) {
            #pragma unroll
            for (int tc = 0; tc < 4; tc++) {
                acc[tr][tc] = __builtin_amdgcn_mfma_f32_16x16x32_bf16(ah[tr], bh[tc], acc[tr][tc], 0, 0, 0);
                acc[tr][tc] = __builtin_amdgcn_mfma_f32_16x16x32_bf16(ah[tr], bl[tc], acc[tr][tc], 0, 0, 0);
                acc[tr][tc] = __builtin_amdgcn_mfma_f32_16x16x32_bf16(al[tr], bh[tc], acc[tr][tc], 0, 0, 0);
            }
        }
    }

    // C/D layout: row = (lane>>4)*4 + reg, col = lane&15 (per 16x16 tile)
    #pragma unroll
    for (int tr = 0; tr < 4; tr++) {
        #pragma unroll
        for (int r = 0; r < 4; r++) {
            int row = r0 + tr * 16 + lg * 4 + r;
            if (row < N) {
                float sc = rowscale ? rowscale[row] : 1.0f;
                #pragma unroll
                for (int tc = 0; tc < 4; tc++) {
                    int col = c0 + tc * 16 + l15;
                    float val = acc[tr][tc][r] * sc;
                    if (OUT_F16) {
                        ((__half*)outp)[(size_t)row * 128 + col] = __float2half(val);
                    } else {
                        ((float*)outp)[(size_t)row * 128 + col] = val;
                    }
                }
            }
        }
    }
}

// ---------------- gather (fp16 in, fp32 out): out[d] = dinv[d]*(sum hws[s] + hws[d]) + bias ----------------
__global__ __launch_bounds__(256) void gather_kernel(const __half* __restrict__ hws,
                                                     const int* __restrict__ csr_src,
                                                     const int* __restrict__ offs,
                                                     const float* __restrict__ dinv,
                                                     const float* __restrict__ bias,
                                                     float* __restrict__ out,
                                                     int N, int relu) {
    int lane = threadIdx.x & 63;
    int node = blockIdx.x * 4 + (threadIdx.x >> 6);
    if (node >= N) return;
    int lo = offs[node], hi = offs[node + 1];

    float2 acc = make_float2(0.f, 0.f);
    int j = lo;
    for (; j + 3 < hi; j += 4) {
        int s0 = csr_src[j], s1 = csr_src[j + 1], s2 = csr_src[j + 2], s3 = csr_src[j + 3];
        float2 v0 = __half22float2(((const __half2*)(hws + (size_t)s0 * HDIM))[lane]);
        float2 v1 = __half22float2(((const __half2*)(hws + (size_t)s1 * HDIM))[lane]);
        float2 v2 = __half22float2(((const __half2*)(hws + (size_t)s2 * HDIM))[lane]);
        float2 v3 = __half22float2(((const __half2*)(hws + (size_t)s3 * HDIM))[lane]);
        acc.x += v0.x + v1.x + v2.x + v3.x;
        acc.y += v0.y + v1.y + v2.y + v3.y;
    }
    for (; j < hi; j++) {
        int s = csr_src[j];
        float2 v = __half22float2(((const __half2*)(hws + (size_t)s * HDIM))[lane]);
        acc.x += v.x; acc.y += v.y;
    }
    float2 vs = __half22float2(((const __half2*)(hws + (size_t)node * HDIM))[lane]);
    float di = dinv[node];
    float2 b = ((const float2*)bias)[lane];
    float ox = di * (acc.x + vs.x) + b.x;
    float oy = di * (acc.y + vs.y) + b.y;
    if (relu) { ox = fmaxf(ox, 0.f); oy = fmaxf(oy, 0.f); }
    ((float2*)(out + (size_t)node * HDIM))[lane] = make_float2(ox, oy);
}

// ---------------- batchnorm stats: per-feature sum & sumsq ----------------
__global__ __launch_bounds__(256) void bn_stats_kernel(const float* __restrict__ h,
                                                       float* __restrict__ stats, int N) {
    int f = threadIdx.x & 127;
    int half_ = threadIdx.x >> 7;
    float s = 0.f, s2 = 0.f;
    for (int n = blockIdx.x * 2 + half_; n < N; n += gridDim.x * 2) {
        float v = h[(size_t)n * HDIM + f];
        s += v;
        s2 += v * v;
    }
    __shared__ float ls[256], ls2[256];
    ls[threadIdx.x] = s;
    ls2[threadIdx.x] = s2;
    __syncthreads();
    if (half_ == 0) {
        s = ls[f] + ls[f + 128];
        s2 = ls2[f] + ls2[f + 128];
        atomicAdd(&stats[f], s);
        atomicAdd(&stats[128 + f], s2);
    }
}

// ---------------- bn finalize: s = g*rsqrt(var+eps), t = b - m*s ----------------
__global__ void bn_finalize(const float* __restrict__ stats, const float* __restrict__ gamma,
                            const float* __restrict__ beta, float* __restrict__ aff_s,
                            float* __restrict__ aff_t, int N) {
    int f = threadIdx.x;  // 128
    float inv = 1.0f / (float)N;
    float m = stats[f] * inv;
    float var = stats[128 + f] * inv - m * m;
    float s = gamma[f] * rsqrtf(var + 1e-5f);
    aff_s[f] = s;
    aff_t[f] = beta[f] - m * s;
}

// ---------------- pool ----------------
__device__ __forceinline__ int lower_bound_i(const int* __restrict__ arr, int n, int val) {
    int lo = 0, hi = n;
    while (lo < hi) {
        int mid = (lo + hi) >> 1;
        if (arr[mid] < val) lo = mid + 1; else hi = mid;
    }
    return lo;
}

__global__ void pool_kernel(const float* __restrict__ h, const int* __restrict__ batch,
                            float* __restrict__ out, int N, int G) {
    int g = blockIdx.x;
    int lo = lower_bound_i(batch, N, g);
    int hi = lower_bound_i(batch, N, g + 1);
    int f = threadIdx.x;
    float s = 0.f;
    for (int n = lo; n < hi; n++) s += h[(size_t)n * HDIM + f];
    float cnt = (float)(hi - lo);
    out[(size_t)g * HDIM + f] = s / fmaxf(cnt, 1.0f);
}

// ---------------- launch ----------------
extern "C" void kernel_launch(void* const* d_in, const int* in_sizes, int n_in,
                              void* d_out, int out_size, void* d_ws, size_t ws_size,
                              hipStream_t stream) {
    const float* x      = (const float*)d_in[0];
    const int*   ei     = (const int*)d_in[1];
    const int*   batch  = (const int*)d_in[2];
    const float* W_emb  = (const float*)d_in[3];
    const float* b_emb  = (const float*)d_in[4];
    const float* W_conv = (const float*)d_in[5];
    const float* b_conv = (const float*)d_in[6];
    const float* gamma  = (const float*)d_in[7];
    const float* beta   = (const float*)d_in[8];

    const int E = in_sizes[1] / 2;
    const int N = in_sizes[2];
    const int G = out_size / HDIM;
    const int DEPTH = 4;

    const int* srcp = ei;
    const int* dstp = ei + E;
    float* out = (float*)d_out;

    size_t NH = (size_t)N * HDIM;
    size_t npad = ((size_t)N + 63) & ~(size_t)63;
    size_t epad = ((size_t)E + 63) & ~(size_t)63;
    int NB = (N + 255) / 256;

    float* ws = (float*)d_ws;
    float* dinv   = ws;                          // npad
    int*   deg_i  = (int*)(dinv + npad);         // npad
    int*   offs   = deg_i + npad;                // npad + 64
    int*   cursor = offs + npad + 64;            // npad
    int*   bsum   = cursor + npad;               // 256
    int*   csr    = bsum + 256;                  // epad
    float* stats  = (float*)(csr + epad);        // 256
    float* aff_s  = stats + 256;                 // 128
    float* aff_t  = aff_s + 128;                 // 128
    short* wt     = (short*)(aff_t + 128);       // 5 * 2 * 16384 shorts
    float* hbuf   = (float*)(wt + 5 * 2 * 16384);// NH floats
    __half* hws16 = (__half*)(hbuf + NH);        // NH halves (NH/2 floats)

    // ---- weight split (5 matrices: emb + 4 conv) ----
    wsplit_kernel<<<64, 256, 0, stream>>>(W_emb, wt, wt + 16384);
    for (int l = 0; l < DEPTH; l++) {
        short* whi = wt + (size_t)(l + 1) * 32768;
        wsplit_kernel<<<64, 256, 0, stream>>>(W_conv + (size_t)l * 16384, whi, whi + 16384);
    }

    // ---- CSR build ----
    hipMemsetAsync(deg_i, 0, npad * sizeof(int), stream);
    deg_kernel<<<1024, 256, 0, stream>>>(dstp, deg_i, E);
    dinv_kernel<<<(N + 255) / 256, 256, 0, stream>>>(deg_i, dinv, N);
    scan_partial<<<NB, 256, 0, stream>>>(deg_i, offs, bsum, N);
    scan_bsum<<<1, 256, 0, stream>>>(bsum, NB);
    scan_add<<<NB, 256, 0, stream>>>(bsum, offs, N, E);
    hipMemsetAsync(cursor, 0, npad * sizeof(int), stream);
    fill_kernel<<<1024, 256, 0, stream>>>(srcp, dstp, offs, cursor, csr, E);

    int gemm_blocks = (N + 127) / 128;

    // ---- embedding: hbuf = x @ W_emb + b_emb (fp32 out) ----
    gemm_mfma<false><<<gemm_blocks, 256, 0, stream>>>(x, wt, wt + 16384, nullptr, nullptr,
                                                      b_emb, nullptr, hbuf, N);

    int gather_blocks = (N + 3) / 4;

    for (int l = 0; l < DEPTH; l++) {
        short* whi = wt + (size_t)(l + 1) * 32768;
        // hws16 = fp16( dinv .* (BN_affine(hbuf) @ W_conv[l]) )   (affine only for l>0)
        gemm_mfma<true><<<gemm_blocks, 256, 0, stream>>>(hbuf, whi, whi + 16384,
                                                         (l > 0) ? aff_s : nullptr,
                                                         (l > 0) ? aff_t : nullptr,
                                                         nullptr, dinv, hws16, N);
        gather_kernel<<<gather_blocks, 256, 0, stream>>>(hws16, csr, offs, dinv,
                                                         b_conv + (size_t)l * HDIM, hbuf,
                                                         N, (l < DEPTH - 1) ? 1 : 0);
        if (l < DEPTH - 1) {
            hipMemsetAsync(stats, 0, 256 * sizeof(float), stream);
            bn_stats_kernel<<<512, 256, 0, stream>>>(hbuf, stats, N);
            bn_finalize<<<1, 128, 0, stream>>>(stats, gamma + (size_t)l * HDIM,
                                               beta + (size_t)l * HDIM, aff_s, aff_t, N);
        }
    }

    pool_kernel<<<G, HDIM, 0, stream>>>(hbuf, batch, out, N, G);
}